// Round 2
// baseline (363.820 us; speedup 1.0000x reference)
//
#include <hip/hip_runtime.h>
#include <math.h>

#define NFIELD 3
#define FEAT 256   // D == O == 256

typedef __attribute__((ext_vector_type(8))) short frag_ab;   // 8 bf16 (4 VGPRs)
typedef __attribute__((ext_vector_type(4))) float frag_cd;   // 4 fp32 acc

__device__ __forceinline__ unsigned short f2bf(float f) {
    unsigned int u = __float_as_uint(f);
    u = (u + 0x7fffu + ((u >> 16) & 1u)) >> 16;   // RNE
    return (unsigned short)u;
}
__device__ __forceinline__ float bf2f(unsigned short b) {
    return __uint_as_float(((unsigned int)b) << 16);
}

// ---------------- CSR build: count / scan / fill ----------------

__global__ void k_zero(float* dnrm, int* count, int n) {
    int i = blockIdx.x * blockDim.x + threadIdx.x;
    if (i < n) { dnrm[i] = 2.0f; count[i] = 0; }   // improved self-loop weight 2.0
}

__global__ void k_count(const int* __restrict__ col, const float* __restrict__ w,
                        float* dnrm, int* count, int E) {
    int e = blockIdx.x * blockDim.x + threadIdx.x;
    if (e < E) {
        int c = col[e];
        atomicAdd(&count[c], 1);
        atomicAdd(&dnrm[c], w[e]);
    }
}

#define SCAN_T 1024
__global__ __launch_bounds__(SCAN_T) void k_scan(const int* __restrict__ count,
        float* dnrm, int* rowptr, int* cursor, int n, int E) {
    __shared__ int part[SCAN_T];
    int t = threadIdx.x;
    int ch = (n + SCAN_T - 1) / SCAN_T;
    int c0 = t * ch, c1 = min(n, c0 + ch);
    int s = 0;
    for (int c = c0; c < c1; ++c) s += count[c];
    part[t] = s;
    __syncthreads();
    for (int off = 1; off < SCAN_T; off <<= 1) {
        int v = (t >= off) ? part[t - off] : 0;
        __syncthreads();
        part[t] += v;
        __syncthreads();
    }
    int base = part[t] - s;   // exclusive prefix
    for (int c = c0; c < c1; ++c) {
        rowptr[c] = base; cursor[c] = base; base += count[c];
        float d = dnrm[c];
        dnrm[c] = d > 0.0f ? rsqrtf(d) : 0.0f;
    }
    if (t == 0) rowptr[n] = E;
}

// fill packed edge records: (src row, precomputed norm)
__global__ void k_fill(const int* __restrict__ ei, const float* __restrict__ ew,
                       const float* __restrict__ dnrm, int* cursor,
                       int2* __restrict__ erec, int E) {
    int e = blockIdx.x * blockDim.x + threadIdx.x;
    if (e < E) {
        int r = ei[e];
        int c = ei[E + e];
        float nm = dnrm[r] * ew[e] * dnrm[c];
        int p = atomicAdd(&cursor[c], 1);
        erec[p] = make_int2(r, __float_as_int(nm));
    }
}

// ---------------- conversions ----------------

__global__ void k_cvt_x(const float* __restrict__ src, unsigned short* __restrict__ dst,
                        int count4) {
    int i = blockIdx.x * blockDim.x + threadIdx.x;
    if (i >= count4) return;
    float4 v = *((const float4*)src + i);
    ushort4 o;
    o.x = f2bf(v.x); o.y = f2bf(v.y); o.z = f2bf(v.z); o.w = f2bf(v.w);
    *((ushort4*)dst + i) = o;
}

// weights -> bf16, all in [f][o][k] layout (Wg/Wh transposed, Wr straight)
__global__ void k_cvt_w(const float* __restrict__ Wg, const float* __restrict__ Wr,
                        const float* __restrict__ Wh,
                        unsigned short* __restrict__ wgT, unsigned short* __restrict__ wrT,
                        unsigned short* __restrict__ whT) {
    int i = blockIdx.x * blockDim.x + threadIdx.x;          // over NFIELD*256*256
    if (i >= NFIELD * FEAT * FEAT) return;
    int f = i >> 16;
    int r = i & 0xffff;
    int d = r >> 8;          // k index in source row-major [d][o]
    int o = r & 255;
    int tdst = (f << 16) | (o << 8) | d;
    wgT[tdst] = f2bf(Wg[i]);
    whT[tdst] = f2bf(Wh[i]);
    wrT[i]    = f2bf(Wr[i]);   // already [o][k]
}

// ---------------- gather, XCD-sliced ----------------
// R2 theory: gather was LLC-bound because the 30.7MB source working set thrashes
// each XCD's 4MiB L2 (FETCH 227MB vs 491MB logical = 54% hit). Split into
// units = (field, feat-quarter, dest-half): per-unit source working set =
// n*64 feats*2B = 2.56MB < 4MiB. Pin unit -> XCD via blockIdx%8 round-robin
// (perf heuristic only; correctness independent of mapping).
// 16-lane group per dest node: lane reads 8B => 128B = one quarter-row.
__global__ void k_gather_sl(const int2* __restrict__ erec,
                            const float* __restrict__ dnrm, const int* __restrict__ rowptr,
                            const unsigned short* __restrict__ xb,
                            unsigned short* __restrict__ xab,
                            int n, int fl_count, int nchunk) {
    int b = blockIdx.x;
    int xcd = b & 7;
    int j = b >> 3;
    int phase = j / nchunk;
    int c = j - phase * nchunk;
    int u = xcd + 8 * phase;              // unit id
    int units = fl_count * 8;             // fields * 4 quarters * 2 dest-halves
    if (u >= units) return;
    int s  = u >> 1;                      // (field, quarter)
    int dh = u & 1;                       // dest half
    int f  = s >> 2;
    int q  = s & 3;

    int t = threadIdx.x;
    int g = t >> 4;                       // group 0..15 (one dest each)
    int fl_lane = t & 15;

    int half_len = (n + 1) >> 1;
    int local = c * 16 + g;
    int d = dh * half_len + local;
    bool valid = (local < half_len) && (d < n);

    const size_t nf = (size_t)n * FEAT;
    const unsigned short* xf = xb  + (size_t)f * nf + q * 64;   // quarter base
    unsigned short*       xo = xab + (size_t)f * nf + q * 64;

    float a0 = 0.f, a1 = 0.f, a2 = 0.f, a3 = 0.f;
    int beg = 0, end = 0;
    if (valid) {
        beg = rowptr[d]; end = rowptr[d + 1];
        float dc = dnrm[d];
        float sc = 2.0f * dc * dc;
        ushort4 v = ((const ushort4*)(xf + (size_t)d * FEAT))[fl_lane];
        a0 = sc * bf2f(v.x); a1 = sc * bf2f(v.y);
        a2 = sc * bf2f(v.z); a3 = sc * bf2f(v.w);
    }

    int i = beg;
    for (; i + 1 < end; i += 2) {         // per-group bounds; exec-masked divergence
        int2 ra = erec[i];
        int2 rb = erec[i + 1];
        ushort4 va = ((const ushort4*)(xf + (size_t)ra.x * FEAT))[fl_lane];
        ushort4 vb = ((const ushort4*)(xf + (size_t)rb.x * FEAT))[fl_lane];
        float na = __int_as_float(ra.y);
        float nb = __int_as_float(rb.y);
        a0 += na * bf2f(va.x) + nb * bf2f(vb.x);
        a1 += na * bf2f(va.y) + nb * bf2f(vb.y);
        a2 += na * bf2f(va.z) + nb * bf2f(vb.z);
        a3 += na * bf2f(va.w) + nb * bf2f(vb.w);
    }
    if (i < end) {
        int2 ra = erec[i];
        ushort4 va = ((const ushort4*)(xf + (size_t)ra.x * FEAT))[fl_lane];
        float na = __int_as_float(ra.y);
        a0 += na * bf2f(va.x); a1 += na * bf2f(va.y);
        a2 += na * bf2f(va.z); a3 += na * bf2f(va.w);
    }

    if (valid) {
        ushort4 o;
        o.x = f2bf(a0); o.y = f2bf(a1); o.z = f2bf(a2); o.w = f2bf(a3);
        ((ushort4*)(xo + (size_t)d * FEAT))[fl_lane] = o;
    }
}

// ---------------- MFMA GEMM + highway + leaky_relu ----------------
// out[f,m,o] = leaky( g*(xa.WgT^T) + (1-g)*(x.WrT^T) ), g = sigmoid(x.WhT^T)
// weights in [o][k]; LDS tiles [row][k] with XOR quad swizzle (0 conflicts, R4-verified).
// 64x128 block tile: A read 2x from memory (was 4x), 24 MFMA : 14 ds_read per wave-iter.
#define BM 64
#define BN 128
#define BK 32

__device__ __forceinline__ int swz(int row, int quad) {
    return (quad ^ ((row >> 1) & 3)) * 8;
}

__global__ __launch_bounds__(256) void k_gemm_mfma(
    const unsigned short* __restrict__ xb, const unsigned short* __restrict__ xab,
    const unsigned short* __restrict__ wgT, const unsigned short* __restrict__ wrT,
    const unsigned short* __restrict__ whT,
    float* __restrict__ out, int n, int f_base) {

    __shared__ unsigned short As_x[BM][BK];
    __shared__ unsigned short As_a[BM][BK];
    __shared__ unsigned short Bs[3][BN][BK];   // g, r, h

    int fl = blockIdx.z;
    int f  = f_base + fl;
    int m0 = blockIdx.x * BM;
    int o0 = blockIdx.y * BN;
    int t  = threadIdx.x;

    const unsigned short* xf  = xb  + (size_t)fl * n * FEAT;
    const unsigned short* xaf = xab + (size_t)fl * n * FEAT;
    const unsigned short* wsrc0 = wgT + ((size_t)f << 16);
    const unsigned short* wsrc1 = wrT + ((size_t)f << 16);
    const unsigned short* wsrc2 = whT + ((size_t)f << 16);

    int w    = t >> 6;
    int lane = t & 63;
    int lrow = lane & 15;
    int quad = lane >> 4;
    int wn   = w * 32;      // wave's 32-col window of the 128-wide tile

    frag_cd acc[3][4][2];   // stream (g,r,h), mi, ni
    #pragma unroll
    for (int s = 0; s < 3; ++s)
        #pragma unroll
        for (int mi = 0; mi < 4; ++mi)
            #pragma unroll
            for (int ni = 0; ni < 2; ++ni)
                acc[s][mi][ni] = (frag_cd){0.f, 0.f, 0.f, 0.f};

    // A staging: thread t -> row t>>2 (0..63), 16B chunk t&3
    int arow = t >> 2;
    int aq   = (t & 3) * 8;
    int adst = swz(arow, t & 3);
    int am   = min(m0 + arow, n - 1);           // clamp loads; stores guarded

    for (int k0 = 0; k0 < FEAT; k0 += BK) {
        *(uint4*)&As_x[arow][adst] = *(const uint4*)(xf  + (size_t)am * FEAT + k0 + aq);
        *(uint4*)&As_a[arow][adst] = *(const uint4*)(xaf + (size_t)am * FEAT + k0 + aq);
        #pragma unroll
        for (int s = 0; s < 6; ++s) {
            int buf = s >> 1;                          // uniform per unrolled s
            int row = (s & 1) * 64 + (t >> 2);         // 0..127
            const unsigned short* wsrc = (buf == 0) ? wsrc0 : (buf == 1) ? wsrc1 : wsrc2;
            *(uint4*)&Bs[buf][row][swz(row, t & 3)] =
                *(const uint4*)(wsrc + ((o0 + row) << 8) + k0 + aq);
        }
        __syncthreads();

        frag_ab ax[4], aa[4], bg[2], br[2], bh[2];
        #pragma unroll
        for (int mi = 0; mi < 4; ++mi) {
            int r = mi * 16 + lrow;
            int c = swz(r, quad);
            ax[mi] = *(const frag_ab*)&As_x[r][c];
            aa[mi] = *(const frag_ab*)&As_a[r][c];
        }
        #pragma unroll
        for (int ni = 0; ni < 2; ++ni) {
            int r = wn + ni * 16 + lrow;
            int c = swz(r, quad);
            bg[ni] = *(const frag_ab*)&Bs[0][r][c];
            br[ni] = *(const frag_ab*)&Bs[1][r][c];
            bh[ni] = *(const frag_ab*)&Bs[2][r][c];
        }
        #pragma unroll
        for (int mi = 0; mi < 4; ++mi)
            #pragma unroll
            for (int ni = 0; ni < 2; ++ni) {
                acc[0][mi][ni] = __builtin_amdgcn_mfma_f32_16x16x32_bf16(aa[mi], bg[ni], acc[0][mi][ni], 0, 0, 0);
                acc[1][mi][ni] = __builtin_amdgcn_mfma_f32_16x16x32_bf16(ax[mi], br[ni], acc[1][mi][ni], 0, 0, 0);
                acc[2][mi][ni] = __builtin_amdgcn_mfma_f32_16x16x32_bf16(ax[mi], bh[ni], acc[2][mi][ni], 0, 0, 0);
            }
        __syncthreads();
    }

    // epilogue: C/D layout col=lane&15, row=quad*4+i (m89/m91-verified)
    #pragma unroll
    for (int mi = 0; mi < 4; ++mi)
        #pragma unroll
        for (int ni = 0; ni < 2; ++ni)
            #pragma unroll
            for (int i = 0; i < 4; ++i) {
                int grow = m0 + mi * 16 + quad * 4 + i;
                if (grow >= n) continue;
                float h = acc[2][mi][ni][i];
                float g = 1.0f / (1.0f + __expf(-h));
                float v = g * acc[0][mi][ni][i] + (1.0f - g) * acc[1][mi][ni][i];
                v = v >= 0.0f ? v : 0.01f * v;
                out[((size_t)f * n + grow) * FEAT + o0 + wn + ni * 16 + lrow] = v;
            }
}

// ---------------- launcher ----------------

static inline size_t align_up(size_t v, size_t a) { return (v + a - 1) & ~(a - 1); }

extern "C" void kernel_launch(void* const* d_in, const int* in_sizes, int n_in,
                              void* d_out, int out_size, void* d_ws, size_t ws_size,
                              hipStream_t stream) {
    const float* x  = (const float*)d_in[0];
    const int*   ei = (const int*)d_in[1];
    const float* ew = (const float*)d_in[2];
    const float* Wg = (const float*)d_in[3];
    const float* Wr = (const float*)d_in[4];
    const float* Wh = (const float*)d_in[5];
    float* out = (float*)d_out;

    const int n = in_sizes[0] / (NFIELD * FEAT);   // 20000
    const int E = in_sizes[2];                     // 320000

    char* base = (char*)d_ws;
    size_t off = 0;
    float* dnrm   = (float*)(base + off); off = align_up(off + (size_t)n * 4, 256);
    int*   count  = (int*)  (base + off); off = align_up(off + (size_t)n * 4, 256);
    int*   rowptr = (int*)  (base + off); off = align_up(off + (size_t)(n + 1) * 4, 256);
    int*   cursor = (int*)  (base + off); off = align_up(off + (size_t)n * 4, 256);
    int2*  erec   = (int2*) (base + off); off = align_up(off + (size_t)E * 8, 256);
    unsigned short* wgT = (unsigned short*)(base + off); off = align_up(off + (size_t)NFIELD * FEAT * FEAT * 2, 256);
    unsigned short* wrT = (unsigned short*)(base + off); off = align_up(off + (size_t)NFIELD * FEAT * FEAT * 2, 256);
    unsigned short* whT = (unsigned short*)(base + off); off = align_up(off + (size_t)NFIELD * FEAT * FEAT * 2, 256);
    size_t fixed = off;

    const size_t per_field = (size_t)n * FEAT * 2;   // bf16
    int fl;
    if (ws_size >= fixed + 2 * (size_t)NFIELD * per_field + 1024) fl = NFIELD;
    else fl = 1;
    unsigned short* xb  = (unsigned short*)(base + fixed);
    unsigned short* xab = (unsigned short*)(base + align_up(fixed + (size_t)fl * per_field, 256));

    const int* col = ei + E;

    // CSR build + normalization (shared across fields)
    k_zero <<<(n + 255) / 256, 256, 0, stream>>>(dnrm, count, n);
    k_count<<<(E + 255) / 256, 256, 0, stream>>>(col, ew, dnrm, count, E);
    k_scan <<<1, SCAN_T, 0, stream>>>(count, dnrm, rowptr, cursor, n, E);
    k_fill <<<(E + 255) / 256, 256, 0, stream>>>(ei, ew, dnrm, cursor, erec, E);

    // weights -> bf16 [o][k]
    {
        int cnt = NFIELD * FEAT * FEAT;
        k_cvt_w<<<(cnt + 255) / 256, 256, 0, stream>>>(Wg, Wr, Wh, wgT, wrT, whT);
    }

    // gather slicing: units = fl*8 (field x quarter x dest-half), 8 units per phase
    int half_len = (n + 1) / 2;
    int nchunk = (half_len + 15) / 16;           // 16 dests per block
    int phases = (fl * 8 + 7) / 8;               // fl=3 -> 3, fl=1 -> 1
    int gsl_blocks = 8 * phases * nchunk;

    dim3 ggemm((n + BM - 1) / BM, FEAT / BN, fl);

    if (fl == NFIELD) {
        int cnt4 = NFIELD * n * FEAT / 4;
        k_cvt_x<<<(cnt4 + 255) / 256, 256, 0, stream>>>(x, xb, cnt4);
        k_gather_sl<<<gsl_blocks, 256, 0, stream>>>(erec, dnrm, rowptr, xb, xab, n, NFIELD, nchunk);
        k_gemm_mfma<<<ggemm, 256, 0, stream>>>(xb, xab, wgT, wrT, whT, out, n, 0);
    } else {
        for (int f = 0; f < NFIELD; ++f) {
            int cnt4 = n * FEAT / 4;
            k_cvt_x<<<(cnt4 + 255) / 256, 256, 0, stream>>>(x + (size_t)f * n * FEAT, xb, cnt4);
            k_gather_sl<<<gsl_blocks, 256, 0, stream>>>(erec, dnrm, rowptr, xb, xab, n, 1, nchunk);
            k_gemm_mfma<<<ggemm, 256, 0, stream>>>(xb, xab, wgT, wrT, whT, out, n, f);
        }
    }
}